// Round 12
// baseline (247.764 us; speedup 1.0000x reference)
//
#include <hip/hip_runtime.h>
#include <hip/hip_bf16.h>

#define B_ 2048
#define P_ 32
#define Q_ 65
#define O_ 16
#define H_ 32

typedef __attribute__((ext_vector_type(8))) short short8;
typedef __attribute__((ext_vector_type(4))) float f32x4;

union F4S8 { float4 f; short8 s; unsigned u[4]; };

#if defined(__has_builtin)
# if __has_builtin(__builtin_amdgcn_exp2f)
#  define HAVE_EXP2 1
# endif
#endif
#ifdef HAVE_EXP2
#define SCALE_K 2.8853900817779268f   // 2*log2(e)
__device__ __forceinline__ float exp_z(float y) { return __builtin_amdgcn_exp2f(y); }
#else
#define SCALE_K 2.0f
__device__ __forceinline__ float exp_z(float y) { return __expf(y); }
#endif

// sigmoid-complement: s = 1/(e^{2z}+1) given y = SCALE_K*z.  tanh(z) = 1 - 2s.
__device__ __forceinline__ float sigc(float y) {
    return __builtin_amdgcn_rcpf(exp_z(y) + 1.0f);
}

__device__ __forceinline__ unsigned short bf_rne(float f) {
    unsigned u = __float_as_uint(f);
    return (unsigned short)((u + 0x7FFFu + ((u >> 16) & 1u)) >> 16);
}

// packed bf16 pair (RNE): low16 = bf16(a), high16 = bf16(b)
__device__ __forceinline__ unsigned pk_bf16(float a, float b) {
    __hip_bfloat162 h = __float22bfloat162_rn(make_float2(a, b));
    return *reinterpret_cast<unsigned*>(&h);
}

// In-register record per (pq,lane).
struct Rec {
    float4 w1a, w1b, b1a, b1b;   // K-prescaled layer-1 weights/biases (g-group)
    float4 h0, l0, h1, l1;       // hi/lo bf16 of  -2*K*W2  fragments
    float4 ms;                    // {K*(b2+colsum)[c], same[c+16], -2w3[c], -2w3[c+16]}
};

// MODE2 layouts:
//  fragc[pq]: 4 chunks x 64 lanes x 16B  (float4 idx = pq*256 + k*64 + lane)
//  shw[pq]:   128 floats: [0:32) K*w1, [32:64) K*b1,
//             [64:128) per-col float4 {K*(b2+cs)[c], K*(b2+cs)[c+16], -2w3[c], -2w3[c+16]}
template<int MODE>
__device__ __forceinline__ Rec load_rec(
    const float* __restrict__ fragc, const float* __restrict__ shw,
    const float* __restrict__ w1, const float* __restrict__ b1,
    const float* __restrict__ w2, const float* __restrict__ b2,
    const float* __restrict__ w3,
    int pq, int lane, int g, int col)
{
    Rec r;
    if (MODE == 2) {
        const float4* fp = reinterpret_cast<const float4*>(fragc) + (size_t)pq * 256 + lane;
        r.h0 = fp[0]; r.l0 = fp[64]; r.h1 = fp[128]; r.l1 = fp[192];
        const float4* a = reinterpret_cast<const float4*>(shw + (size_t)pq * 128);
        r.w1a = a[g * 2];     r.w1b = a[g * 2 + 1];
        r.b1a = a[8 + g * 2]; r.b1b = a[8 + g * 2 + 1];
        r.ms  = a[16 + col];
    } else {
        // Fallback: build the transformed record from raw inputs (slow path).
        const float4* w1p = reinterpret_cast<const float4*>(w1 + pq * H_ + g * 8);
        r.w1a = w1p[0]; r.w1b = w1p[1];
        const float4* b1p = reinterpret_cast<const float4*>(b1 + pq * H_ + g * 8);
        r.b1a = b1p[0]; r.b1b = b1p[1];
        const float* w2p = w2 + (size_t)pq * (H_ * H_);
        F4S8 u0, u1, u2, u3;
        float cs0 = 0.f, cs1 = 0.f;
        #pragma unroll
        for (int jj = 0; jj < 8; ++jj) {
            float v0 = -2.f * SCALE_K * w2p[(g * 8 + jj) * H_ + col];
            float v1 = -2.f * SCALE_K * w2p[(g * 8 + jj) * H_ + 16 + col];
            unsigned q0 = __float_as_uint(v0);
            u0.s[jj] = (short)(q0 >> 16);
            u1.s[jj] = (short)(__float_as_uint(v0 - __uint_as_float(q0 & 0xFFFF0000u)) >> 16);
            unsigned q1 = __float_as_uint(v1);
            u2.s[jj] = (short)(q1 >> 16);
            u3.s[jj] = (short)(__float_as_uint(v1 - __uint_as_float(q1 & 0xFFFF0000u)) >> 16);
        }
        for (int h = 0; h < H_; ++h) {
            cs0 += w2p[h * H_ + col];
            cs1 += w2p[h * H_ + 16 + col];
        }
        r.h0 = u0.f; r.l0 = u1.f; r.h1 = u2.f; r.l1 = u3.f;
        r.ms = make_float4(SCALE_K * (b2[pq * H_ + col] + cs0),
                           SCALE_K * (b2[pq * H_ + 16 + col] + cs1),
                           -2.f * w3[pq * H_ + col],
                           -2.f * w3[pq * H_ + 16 + col]);
    }
    return r;
}

// One eval for 16 batch rows per wave; psum accumulates layer-3 partials.
template<bool PRE>
__device__ __forceinline__ void eval_rec(const Rec& r, float xv, float psum[4])
{
    float s0 = sigc(PRE ? fmaf(xv, r.w1a.x, r.b1a.x) : SCALE_K * fmaf(xv, r.w1a.x, r.b1a.x));
    float s1 = sigc(PRE ? fmaf(xv, r.w1a.y, r.b1a.y) : SCALE_K * fmaf(xv, r.w1a.y, r.b1a.y));
    float s2 = sigc(PRE ? fmaf(xv, r.w1a.z, r.b1a.z) : SCALE_K * fmaf(xv, r.w1a.z, r.b1a.z));
    float s3 = sigc(PRE ? fmaf(xv, r.w1a.w, r.b1a.w) : SCALE_K * fmaf(xv, r.w1a.w, r.b1a.w));
    float s4 = sigc(PRE ? fmaf(xv, r.w1b.x, r.b1b.x) : SCALE_K * fmaf(xv, r.w1b.x, r.b1b.x));
    float s5 = sigc(PRE ? fmaf(xv, r.w1b.y, r.b1b.y) : SCALE_K * fmaf(xv, r.w1b.y, r.b1b.y));
    float s6 = sigc(PRE ? fmaf(xv, r.w1b.z, r.b1b.z) : SCALE_K * fmaf(xv, r.w1b.z, r.b1b.z));
    float s7 = sigc(PRE ? fmaf(xv, r.w1b.w, r.b1b.w) : SCALE_K * fmaf(xv, r.w1b.w, r.b1b.w));

    // hi via cvt_pk (RNE); lo = s - hi (exact in f32), cvt_pk again.
    F4S8 hi, lo;
    hi.u[0] = pk_bf16(s0, s1); hi.u[1] = pk_bf16(s2, s3);
    hi.u[2] = pk_bf16(s4, s5); hi.u[3] = pk_bf16(s6, s7);
    float l0v = s0 - __uint_as_float(hi.u[0] << 16);
    float l1v = s1 - __uint_as_float(hi.u[0] & 0xFFFF0000u);
    float l2v = s2 - __uint_as_float(hi.u[1] << 16);
    float l3v = s3 - __uint_as_float(hi.u[1] & 0xFFFF0000u);
    float l4v = s4 - __uint_as_float(hi.u[2] << 16);
    float l5v = s5 - __uint_as_float(hi.u[2] & 0xFFFF0000u);
    float l6v = s6 - __uint_as_float(hi.u[3] << 16);
    float l7v = s7 - __uint_as_float(hi.u[3] & 0xFFFF0000u);
    lo.u[0] = pk_bf16(l0v, l1v); lo.u[1] = pk_bf16(l2v, l3v);
    lo.u[2] = pk_bf16(l4v, l5v); lo.u[3] = pk_bf16(l6v, l7v);

    F4S8 c0, c1, c2, c3;
    c0.f = r.h0; c1.f = r.l0; c2.f = r.h1; c3.f = r.l1;
    f32x4 acc0 = {r.ms.x, r.ms.x, r.ms.x, r.ms.x};
    f32x4 acc1 = {r.ms.y, r.ms.y, r.ms.y, r.ms.y};
    acc0 = __builtin_amdgcn_mfma_f32_16x16x32_bf16(hi.s, c0.s, acc0, 0, 0, 0);
    acc0 = __builtin_amdgcn_mfma_f32_16x16x32_bf16(lo.s, c0.s, acc0, 0, 0, 0);
    acc0 = __builtin_amdgcn_mfma_f32_16x16x32_bf16(hi.s, c1.s, acc0, 0, 0, 0);
    acc1 = __builtin_amdgcn_mfma_f32_16x16x32_bf16(hi.s, c2.s, acc1, 0, 0, 0);
    acc1 = __builtin_amdgcn_mfma_f32_16x16x32_bf16(lo.s, c2.s, acc1, 0, 0, 0);
    acc1 = __builtin_amdgcn_mfma_f32_16x16x32_bf16(hi.s, c3.s, acc1, 0, 0, 0);

    #pragma unroll
    for (int rr = 0; rr < 4; ++rr) {
        psum[rr] = fmaf(sigc(acc0[rr]), r.ms.z, psum[rr]);
        psum[rr] = fmaf(sigc(acc1[rr]), r.ms.w, psum[rr]);
    }
}

__device__ __forceinline__ void reduce_store(float psum[4], float b3sum,
                                             int lane, int g, int b0w,
                                             float* addr_base, int stride, bool atomic)
{
    #pragma unroll
    for (int rr = 0; rr < 4; ++rr) {
        psum[rr] += __shfl_xor(psum[rr], 1);
        psum[rr] += __shfl_xor(psum[rr], 2);
        psum[rr] += __shfl_xor(psum[rr], 4);
        psum[rr] += __shfl_xor(psum[rr], 8);
    }
    float v01 = (lane & 1) ? psum[1] : psum[0];
    float v23 = (lane & 1) ? psum[3] : psum[2];
    float v = (lane & 2) ? v23 : v01;
    if ((lane & 15) < 4) {
        int row = b0w + g * 4 + (lane & 3);
        float* a = addr_base + (size_t)row * stride;
        if (atomic) atomicAdd(a, v + b3sum);
        else        *a = v + b3sum;
    }
}

// ---------------------------------------------------------------------------
// Stage 1: sT[q][b] = sum_p psi_{p,q}(x[b,p]).   grid 2080 = 8 x 260.
// ---------------------------------------------------------------------------
template<int MODE>
__global__ __launch_bounds__(256)
void psi_main(const float* __restrict__ x, const float* __restrict__ xT,
              const float* __restrict__ w1, const float* __restrict__ b1,
              const float* __restrict__ w2, const float* __restrict__ b2,
              const float* __restrict__ w3, const float* __restrict__ b3,
              const float* __restrict__ b3c,
              const float* __restrict__ fragc, const float* __restrict__ shw,
              float* __restrict__ sT)
{
    const int id = blockIdx.x;
    const int j = (id & 7) * 260 + (id >> 3);   // bijective: 2080 = 8*260
    const int q = j >> 5;
    const int btile = j & 31;
    const int lane = threadIdx.x & 63;
    const int wid = threadIdx.x >> 6;
    const int g = lane >> 4, col = lane & 15;
    const int b0w = btile * 64 + wid * 16;

    float psum[4] = {0.f, 0.f, 0.f, 0.f};
    float b3sum = (MODE == 2) ? b3c[q] : 0.f;

    Rec cur = load_rec<MODE>(fragc, shw, w1, b1, w2, b2, w3, q, lane, g, col);
    float xv = (MODE == 2) ? xT[b0w + col] : x[(size_t)(b0w + col) * P_];

    #pragma unroll 2
    for (int p = 0; p < P_; ++p) {
        const int pn = (p + 1 < P_) ? p + 1 : P_ - 1;
        Rec nxt = load_rec<MODE>(fragc, shw, w1, b1, w2, b2, w3,
                                 pn * Q_ + q, lane, g, col);
        float xn = (MODE == 2) ? xT[(size_t)pn * B_ + b0w + col]
                               : x[(size_t)(b0w + col) * P_ + pn];
        if (MODE != 2) {
            float ws = 0.f;
            for (int h = 0; h < H_; ++h) ws += w3[(p * Q_ + q) * H_ + h];
            b3sum += b3[p * Q_ + q] + ws;
        }
        eval_rec<(MODE == 2)>(cur, xv, psum);
        cur = nxt; xv = xn;
    }

    reduce_store(psum, b3sum, lane, g, b0w, sT + (size_t)q * B_, 1, false);
}

// ---------------------------------------------------------------------------
// Stage 2: out[b][o] += sum_{q in group} phi_{q,o}(sT[q][b]).
// grid 2048 = 8 x 256 (bijective, exactly 8 blocks/CU); 4 q-groups {17,16,16,16}.
// ---------------------------------------------------------------------------
template<int MODE>
__global__ __launch_bounds__(256)
void phi_main(const float* __restrict__ sT,
              const float* __restrict__ w1, const float* __restrict__ b1,
              const float* __restrict__ w2, const float* __restrict__ b2,
              const float* __restrict__ w3, const float* __restrict__ b3,
              const float* __restrict__ b3g,
              const float* __restrict__ fragc, const float* __restrict__ shw,
              float* __restrict__ out)
{
    const int id = blockIdx.x;
    const int j = (id & 7) * 256 + (id >> 3);   // bijective: 2048 = 8*256
    const int qg = j >> 9;                      // 0..3
    const int rem = j & 511;
    const int o = rem >> 5;
    const int btile = rem & 31;
    const int lane = threadIdx.x & 63;
    const int wid = threadIdx.x >> 6;
    const int g = lane >> 4, col = lane & 15;
    const int b0w = btile * 64 + wid * 16;

    const int q0  = (qg == 0) ? 0 : 17 + (qg - 1) * 16;
    const int len = (qg == 0) ? 17 : 16;

    float psum[4] = {0.f, 0.f, 0.f, 0.f};
    float b3sum = (MODE == 2) ? b3g[qg * O_ + o] : 0.f;

    Rec cur = load_rec<MODE>(fragc, shw, w1, b1, w2, b2, w3, q0 * O_ + o, lane, g, col);
    float sv = sT[(size_t)q0 * B_ + b0w + col];

    #pragma unroll 2
    for (int i = 0; i < len; ++i) {
        const int in_ = (i + 1 < len) ? i + 1 : len - 1;
        const int qn = q0 + in_;
        Rec nxt = load_rec<MODE>(fragc, shw, w1, b1, w2, b2, w3,
                                 qn * O_ + o, lane, g, col);
        float sn = sT[(size_t)qn * B_ + b0w + col];
        if (MODE != 2) {
            float ws = 0.f;
            for (int h = 0; h < H_; ++h) ws += w3[((q0 + i) * O_ + o) * H_ + h];
            b3sum += b3[(q0 + i) * O_ + o] + ws;
        }
        eval_rec<(MODE == 2)>(cur, sv, psum);
        cur = nxt; sv = sn;
    }

    // base includes the o-column offset (R5 lesson).
    reduce_store(psum, b3sum, lane, g, b0w, out + o, O_, true);
}

// ---------------------------------------------------------------------------
// Fused prep: fragments (-2K*W2), shw (K*w1, K*b1, K*(b2+colsum), -2w3),
// xT, and b3 tables with folded w3 sums.
// ---------------------------------------------------------------------------
__device__ __forceinline__ void do_frag(const float* __restrict__ w2,
                                        float* __restrict__ frag, int idx)
{
    int pq = idx >> 6, lane = idx & 63;
    int g = lane >> 4, col = lane & 15;
    const float* Wp = w2 + (size_t)pq * (H_ * H_);
    short8 h0v, l0v, h1v, l1v;
    #pragma unroll
    for (int jj = 0; jj < 8; ++jj) {
        float v0 = -2.f * SCALE_K * Wp[(g * 8 + jj) * H_ + col];
        float v1 = -2.f * SCALE_K * Wp[(g * 8 + jj) * H_ + 16 + col];
        unsigned short hb0 = bf_rne(v0);
        h0v[jj] = (short)hb0;
        l0v[jj] = (short)bf_rne(v0 - __uint_as_float(((unsigned)hb0) << 16));
        unsigned short hb1 = bf_rne(v1);
        h1v[jj] = (short)hb1;
        l1v[jj] = (short)bf_rne(v1 - __uint_as_float(((unsigned)hb1) << 16));
    }
    F4S8 a, b, c, d; a.s = h0v; b.s = l0v; c.s = h1v; d.s = l1v;
    float4* op = reinterpret_cast<float4*>(frag) + (size_t)pq * 256 + lane;
    op[0] = a.f; op[64] = b.f; op[128] = c.f; op[192] = d.f;
}

__device__ __forceinline__ void do_shw(const float* __restrict__ w1,
                                       const float* __restrict__ b1,
                                       const float* __restrict__ w2,
                                       const float* __restrict__ b2,
                                       const float* __restrict__ w3,
                                       float* __restrict__ shw, int idx)
{
    int pq = idx >> 7, i = idx & 127;
    float v;
    if (i < 32)       v = SCALE_K * w1[pq * H_ + i];
    else if (i < 64)  v = SCALE_K * b1[pq * H_ + (i - 32)];
    else {
        int c = (i - 64) >> 2, rr = i & 3;
        if (rr <= 1) {
            int cc = c + (rr == 1 ? 16 : 0);
            float cs = 0.f;
            const float* Wp = w2 + (size_t)pq * (H_ * H_);
            for (int h = 0; h < H_; ++h) cs += Wp[h * H_ + cc];
            v = SCALE_K * (b2[pq * H_ + cc] + cs);
        } else {
            int cc = c + (rr == 3 ? 16 : 0);
            v = -2.f * w3[pq * H_ + cc];
        }
    }
    shw[(size_t)pq * 128 + i] = v;
}

#define C1 133120   // psi frag  (P*Q*64)
#define C2 199680   // + phi frag (Q*O*64)
#define C3 465920   // + psi shw  (P*Q*128)
#define C4 599040   // + phi shw  (Q*O*128)
#define C5 664576   // + xT       (B*P)
#define C6 664641   // + b3c      (Q)
#define C7 664705   // + b3g      (64)

__global__ __launch_bounds__(256)
void prep_all(const float* __restrict__ psi_w1, const float* __restrict__ psi_b1,
              const float* __restrict__ psi_w2, const float* __restrict__ psi_b2,
              const float* __restrict__ psi_w3, const float* __restrict__ psi_b3,
              const float* __restrict__ phi_w1, const float* __restrict__ phi_b1,
              const float* __restrict__ phi_w2, const float* __restrict__ phi_b2,
              const float* __restrict__ phi_w3, const float* __restrict__ phi_b3,
              const float* __restrict__ x,
              float* __restrict__ fr1, float* __restrict__ fr2,
              float* __restrict__ sh1, float* __restrict__ sh2,
              float* __restrict__ xT, float* __restrict__ b3c,
              float* __restrict__ b3g)
{
    int t = blockIdx.x * 256 + threadIdx.x;
    if (t < C1) {
        do_frag(psi_w2, fr1, t);
    } else if (t < C2) {
        do_frag(phi_w2, fr2, t - C1);
    } else if (t < C3) {
        do_shw(psi_w1, psi_b1, psi_w2, psi_b2, psi_w3, sh1, t - C2);
    } else if (t < C4) {
        do_shw(phi_w1, phi_b1, phi_w2, phi_b2, phi_w3, sh2, t - C3);
    } else if (t < C5) {
        int idx = t - C4;
        int b = idx >> 5, p = idx & 31;
        xT[(size_t)p * B_ + b] = x[idx];
    } else if (t < C6) {
        int q = t - C5;
        float s = 0.f;
        for (int p = 0; p < P_; ++p) {
            int pq = p * Q_ + q;
            s += psi_b3[pq];
            for (int h = 0; h < H_; ++h) s += psi_w3[pq * H_ + h];
        }
        b3c[q] = s;
    } else if (t < C7) {
        int idx = t - C6;          // qg*16 + o
        int qg = idx >> 4, o = idx & 15;
        int q0  = (qg == 0) ? 0 : 17 + (qg - 1) * 16;
        int len = (qg == 0) ? 17 : 16;
        float s = 0.f;
        for (int i = 0; i < len; ++i) {
            int qo = (q0 + i) * O_ + o;
            s += phi_b3[qo];
            for (int h = 0; h < H_; ++h) s += phi_w3[qo * H_ + h];
        }
        b3g[idx] = s;
    }
}

extern "C" void kernel_launch(void* const* d_in, const int* in_sizes, int n_in,
                              void* d_out, int out_size, void* d_ws, size_t ws_size,
                              hipStream_t stream) {
    const float* x      = (const float*)d_in[0];
    const float* psi_w1 = (const float*)d_in[1];
    const float* psi_b1 = (const float*)d_in[2];
    const float* psi_w2 = (const float*)d_in[3];
    const float* psi_b2 = (const float*)d_in[4];
    const float* psi_w3 = (const float*)d_in[5];
    const float* psi_b3 = (const float*)d_in[6];
    const float* phi_w1 = (const float*)d_in[7];
    const float* phi_b1 = (const float*)d_in[8];
    const float* phi_w2 = (const float*)d_in[9];
    const float* phi_b2 = (const float*)d_in[10];
    const float* phi_w3 = (const float*)d_in[11];
    const float* phi_b3 = (const float*)d_in[12];
    float* out = (float*)d_out;

    const size_t ST  = (size_t)B_ * Q_ * sizeof(float);     //   532,480
    const size_t XT  = (size_t)B_ * P_ * sizeof(float);     //   262,144
    const size_t FR1 = (size_t)P_ * Q_ * 64 * 64;           //  8,519,680
    const size_t FR2 = (size_t)Q_ * O_ * 64 * 64;           //  4,259,840
    const size_t SH1 = (size_t)P_ * Q_ * 128 * 4;           //  1,064,960
    const size_t SH2 = (size_t)Q_ * O_ * 128 * 4;           //    532,480
    const size_t B3C = 320;
    const size_t B3G = 320;

    float* sT = (float*)d_ws;
    hipMemsetAsync(out, 0, (size_t)B_ * O_ * sizeof(float), stream);

    if (ws_size >= ST + XT + FR1 + FR2 + SH1 + SH2 + B3C + B3G) {
        char* base = (char*)d_ws + ST;
        float* xTp  = (float*)base;                   base += XT;
        float* fr1  = (float*)base;                   base += FR1;
        float* fr2  = (float*)base;                   base += FR2;
        float* sh1  = (float*)base;                   base += SH1;
        float* sh2  = (float*)base;                   base += SH2;
        float* b3c  = (float*)base;                   base += B3C;
        float* b3g  = (float*)base;

        prep_all<<<(C7 + 255) / 256, 256, 0, stream>>>(
            psi_w1, psi_b1, psi_w2, psi_b2, psi_w3, psi_b3,
            phi_w1, phi_b1, phi_w2, phi_b2, phi_w3, phi_b3,
            x, fr1, fr2, sh1, sh2, xTp, b3c, b3g);

        psi_main<2><<<2080, 256, 0, stream>>>(
            x, xTp, psi_w1, psi_b1, psi_w2, psi_b2, psi_w3, psi_b3, b3c,
            fr1, sh1, sT);
        phi_main<2><<<2048, 256, 0, stream>>>(
            sT, phi_w1, phi_b1, phi_w2, phi_b2, phi_w3, phi_b3, b3g,
            fr2, sh2, out);
    } else {
        psi_main<0><<<2080, 256, 0, stream>>>(
            x, x, psi_w1, psi_b1, psi_w2, psi_b2, psi_w3, psi_b3, (const float*)sT,
            sT, sT, sT);
        phi_main<0><<<2048, 256, 0, stream>>>(
            sT, phi_w1, phi_b1, phi_w2, phi_b2, phi_w3, phi_b3, (const float*)sT,
            sT, sT, out);
    }
}